// Round 1
// baseline (482.373 us; speedup 1.0000x reference)
//
#include <hip/hip_runtime.h>
#include <stdint.h>
#include <math.h>

#define H0 480
#define W0 640
#define N0 (H0 * W0)
#define NB 32
#define NIMG 64
#define KRANK ((N0 - 1) / 2)

// ---------- helpers ----------

static __device__ __forceinline__ unsigned fkey(float x) {
  unsigned b = __float_as_uint(x);
  return (b & 0x80000000u) ? ~b : (b | 0x80000000u);
}

static __device__ __forceinline__ float blockReduce(float v) {
#pragma unroll
  for (int o = 32; o > 0; o >>= 1) v += __shfl_down(v, o);
  __shared__ float s[16];
  int lane = threadIdx.x & 63, wid = threadIdx.x >> 6;
  if (lane == 0) s[wid] = v;
  __syncthreads();
  int nw = blockDim.x >> 6;
  v = (threadIdx.x < nw) ? s[threadIdx.x] : 0.0f;
  if (wid == 0) {
#pragma unroll
    for (int o = 8; o > 0; o >>= 1) v += __shfl_down(v, o);
  }
  return v;  // valid in thread 0
}

// ---------- init ----------

__global__ void k_init(unsigned* __restrict__ counts, unsigned* __restrict__ prefix,
                       int* __restrict__ kk, double* __restrict__ scsum,
                       double* __restrict__ accum) {
  int t = blockIdx.x * blockDim.x + threadIdx.x;  // exactly 64*256 = 16384 threads
  counts[t] = 0u;
  if (t < NIMG) { prefix[t] = 0u; kk[t] = KRANK; scsum[t] = 0.0; }
  if (t < 8) accum[t] = 0.0;
}

// ---------- radix select (median) ----------

__global__ void k_radix_count(const float* __restrict__ pred, const float* __restrict__ tgt,
                              unsigned* __restrict__ counts, const unsigned* __restrict__ prefix,
                              int pass) {
  __shared__ unsigned h[256][8];  // 8-way replicated to cut LDS-atomic contention
  int img = blockIdx.y;
#pragma unroll
  for (int c = 0; c < 8; ++c) h[threadIdx.x][c] = 0u;
  __syncthreads();
  const float* __restrict__ src = (img < NB) ? (pred + (size_t)img * N0)
                                             : (tgt + (size_t)(img - NB) * N0);
  unsigned long long pref = prefix[img];
  int shiftb = 24 - 8 * pass;
  int copy = threadIdx.x & 7;
  int start = blockIdx.x * blockDim.x + threadIdx.x;
  int stride = gridDim.x * blockDim.x;
  for (int i = start; i < N0; i += stride) {
    unsigned u = fkey(src[i]);
    // 64-bit shift so pass 0 (shift by 32) is well-defined: top 0 bits == prefix 0
    if (((unsigned long long)u >> (shiftb + 8)) == pref)
      atomicAdd(&h[(u >> shiftb) & 255u][copy], 1u);
  }
  __syncthreads();
  unsigned tot = 0;
#pragma unroll
  for (int c = 0; c < 8; ++c) tot += h[threadIdx.x][c];
  if (tot) atomicAdd(&counts[img * 256 + threadIdx.x], tot);
}

__global__ void k_radix_scan(unsigned* __restrict__ counts, unsigned* __restrict__ prefix,
                             int* __restrict__ kk) {
  __shared__ unsigned c[256];
  int img = blockIdx.x;
  c[threadIdx.x] = counts[img * 256 + threadIdx.x];
  __syncthreads();
  if (threadIdx.x == 0) {
    unsigned k = (unsigned)kk[img];
    unsigned cum = 0;
    int b = 0;
    for (; b < 256; ++b) {
      unsigned cb = c[b];
      if (k < cum + cb) break;
      cum += cb;
    }
    prefix[img] = (prefix[img] << 8) | (unsigned)b;
    kk[img] = (int)(k - cum);
  }
  counts[img * 256 + threadIdx.x] = 0u;  // reset for next pass (we read the LDS copy)
}

__global__ void k_median(const unsigned* __restrict__ prefix, float* __restrict__ shiftv) {
  int i = threadIdx.x;  // 64 threads
  unsigned u = prefix[i];
  unsigned bits = (u & 0x80000000u) ? (u ^ 0x80000000u) : ~u;
  shiftv[i] = __uint_as_float(bits);
}

// ---------- scale = mean |x - shift| ----------

__global__ void k_scale(const float* __restrict__ pred, const float* __restrict__ tgt,
                        const float* __restrict__ shiftv, double* __restrict__ scsum) {
  int img = blockIdx.y;
  const float* __restrict__ src = (img < NB) ? (pred + (size_t)img * N0)
                                             : (tgt + (size_t)(img - NB) * N0);
  float sh = shiftv[img];
  float acc = 0.0f;
  int start = blockIdx.x * blockDim.x + threadIdx.x;
  int stride = gridDim.x * blockDim.x;
  for (int i = start; i < N0; i += stride) acc += fabsf(src[i] - sh);
  float r = blockReduce(acc);
  if (threadIdx.x == 0) atomicAdd(&scsum[img], (double)r);
}

// ---------- L1 term on normalized values (on the fly) ----------

__global__ void k_l1(const float* __restrict__ pred, const float* __restrict__ tgt,
                     const float* __restrict__ shiftv, const double* __restrict__ scsum,
                     double* __restrict__ accum) {
  int b = blockIdx.y;
  const float* __restrict__ p = pred + (size_t)b * N0;
  const float* __restrict__ t = tgt + (size_t)b * N0;
  float shp = shiftv[b], sht = shiftv[NB + b];
  float ip = (float)((double)N0 / scsum[b]);
  float it = (float)((double)N0 / scsum[NB + b]);
  float acc = 0.0f;
  int start = blockIdx.x * blockDim.x + threadIdx.x;
  int stride = gridDim.x * blockDim.x;
  for (int i = start; i < N0; i += stride)
    acc += fabsf((p[i] - shp) * ip - (t[i] - sht) * it);
  float r = blockReduce(acc);
  if (threadIdx.x == 0) atomicAdd(&accum[0], (double)r);
}

// ---------- gradient loss, level 0 (raw input, shift cancels, divide by scale) ----------

__global__ void k_grad0(const float* __restrict__ pred, const float* __restrict__ tgt,
                        const double* __restrict__ scsum, double* __restrict__ slot) {
  int b = blockIdx.y;
  const float* __restrict__ p = pred + (size_t)b * N0;
  const float* __restrict__ t = tgt + (size_t)b * N0;
  float ip = (float)((double)N0 / scsum[b]);
  float it = (float)((double)N0 / scsum[NB + b]);
  const int VW = W0 - 2;
  const int NV = (H0 - 2) * VW;
  float acc = 0.0f;
  int start = blockIdx.x * blockDim.x + threadIdx.x;
  int stride = gridDim.x * blockDim.x;
  for (int idx = start; idx < NV; idx += stride) {
    int y = idx / VW, x = idx - y * VW;
    const float* pr = p + (size_t)y * W0 + x;
    float a00 = pr[0], a01 = pr[1], a02 = pr[2];
    float a10 = pr[W0], a12 = pr[W0 + 2];
    float a20 = pr[2 * W0], a21 = pr[2 * W0 + 1], a22 = pr[2 * W0 + 2];
    float gx = 3.0f * (a00 - a02) + 10.0f * (a10 - a12) + 3.0f * (a20 - a22);
    float gy = 3.0f * (a00 - a20) + 10.0f * (a01 - a21) + 3.0f * (a02 - a22);
    float magp = sqrtf(gx * gx + gy * gy) * ip;
    const float* tr = t + (size_t)y * W0 + x;
    float b00 = tr[0], b01 = tr[1], b02 = tr[2];
    float b10 = tr[W0], b12 = tr[W0 + 2];
    float b20 = tr[2 * W0], b21 = tr[2 * W0 + 1], b22 = tr[2 * W0 + 2];
    float hx = 3.0f * (b00 - b02) + 10.0f * (b10 - b12) + 3.0f * (b20 - b22);
    float hy = 3.0f * (b00 - b20) + 10.0f * (b01 - b21) + 3.0f * (b02 - b22);
    float magt = sqrtf(hx * hx + hy * hy) * it;
    acc += fabsf(magp - magt);
  }
  float r = blockReduce(acc);
  if (threadIdx.x == 0) atomicAdd(slot, (double)r);
}

// ---------- gradient loss, generic level (normalized pyramid buffers) ----------

__global__ void k_grad(const float* __restrict__ buf, int H, int W, double* __restrict__ slot) {
  int b = blockIdx.y;
  const float* __restrict__ p = buf + (size_t)b * H * W;
  const float* __restrict__ t = buf + (size_t)(b + NB) * H * W;
  int VW = W - 2;
  int NV = (H - 2) * VW;
  float acc = 0.0f;
  int start = blockIdx.x * blockDim.x + threadIdx.x;
  int stride = gridDim.x * blockDim.x;
  for (int idx = start; idx < NV; idx += stride) {
    int y = idx / VW, x = idx - y * VW;
    const float* pr = p + (size_t)y * W + x;
    float a00 = pr[0], a01 = pr[1], a02 = pr[2];
    float a10 = pr[W], a12 = pr[W + 2];
    float a20 = pr[2 * W], a21 = pr[2 * W + 1], a22 = pr[2 * W + 2];
    float gx = 3.0f * (a00 - a02) + 10.0f * (a10 - a12) + 3.0f * (a20 - a22);
    float gy = 3.0f * (a00 - a20) + 10.0f * (a01 - a21) + 3.0f * (a02 - a22);
    float magp = sqrtf(gx * gx + gy * gy);
    const float* tr = t + (size_t)y * W + x;
    float b00 = tr[0], b01 = tr[1], b02 = tr[2];
    float b10 = tr[W], b12 = tr[W + 2];
    float b20 = tr[2 * W], b21 = tr[2 * W + 1], b22 = tr[2 * W + 2];
    float hx = 3.0f * (b00 - b02) + 10.0f * (b10 - b12) + 3.0f * (b20 - b22);
    float hy = 3.0f * (b00 - b20) + 10.0f * (b01 - b21) + 3.0f * (b02 - b22);
    float magt = sqrtf(hx * hx + hy * hy);
    acc += fabsf(magp - magt);
  }
  float r = blockReduce(acc);
  if (threadIdx.x == 0) atomicAdd(slot, (double)r);
}

// ---------- fused Gauss(pad=2) + 2x2 mean-pool: 6-tap separable [1,5,10,10,5,1]/32 ----------

__global__ void k_down0(const float* __restrict__ pred, const float* __restrict__ tgt,
                        const float* __restrict__ shiftv, const double* __restrict__ scsum,
                        float* __restrict__ out) {
  const float K[6] = {1.0f / 32, 5.0f / 32, 10.0f / 32, 10.0f / 32, 5.0f / 32, 1.0f / 32};
  int img = blockIdx.z;
  int j = blockIdx.x * blockDim.x + threadIdx.x;
  int i = blockIdx.y * blockDim.y + threadIdx.y;
  const int Hout = H0 / 2, Wout = W0 / 2;
  if (i >= Hout || j >= Wout) return;
  const float* __restrict__ src = (img < NB) ? (pred + (size_t)img * N0)
                                             : (tgt + (size_t)(img - NB) * N0);
  float sh = shiftv[img];
  float inv = (float)((double)N0 / scsum[img]);
  float sum = 0.0f;
#pragma unroll
  for (int u = 0; u < 6; ++u) {
    int r = 2 * i - 2 + u;
    if (r < 0 || r >= H0) continue;
    float rs = 0.0f;
#pragma unroll
    for (int v = 0; v < 6; ++v) {
      int c = 2 * j - 2 + v;
      if (c < 0 || c >= W0) continue;
      rs += K[v] * (src[(size_t)r * W0 + c] - sh);
    }
    sum += K[u] * rs;
  }
  out[(size_t)img * Hout * Wout + (size_t)i * Wout + j] = sum * inv;
}

__global__ void k_down(const float* __restrict__ in, float* __restrict__ out, int Hin, int Win) {
  const float K[6] = {1.0f / 32, 5.0f / 32, 10.0f / 32, 10.0f / 32, 5.0f / 32, 1.0f / 32};
  int img = blockIdx.z;
  int j = blockIdx.x * blockDim.x + threadIdx.x;
  int i = blockIdx.y * blockDim.y + threadIdx.y;
  int Hout = Hin / 2, Wout = Win / 2;
  if (i >= Hout || j >= Wout) return;
  const float* __restrict__ src = in + (size_t)img * Hin * Win;
  float sum = 0.0f;
#pragma unroll
  for (int u = 0; u < 6; ++u) {
    int r = 2 * i - 2 + u;
    if (r < 0 || r >= Hin) continue;
    float rs = 0.0f;
#pragma unroll
    for (int v = 0; v < 6; ++v) {
      int c = 2 * j - 2 + v;
      if (c < 0 || c >= Win) continue;
      rs += K[v] * src[(size_t)r * Win + c];
    }
    sum += K[u] * rs;
  }
  out[(size_t)img * Hout * Wout + (size_t)i * Wout + j] = sum;
}

// ---------- finalize ----------

__global__ void k_final(const double* __restrict__ accum, float* __restrict__ out) {
  double l1 = accum[0] / ((double)NB * (double)N0 * 2.0);
  double mage = accum[1] / (478.0 * 638.0) + accum[2] / (238.0 * 318.0) +
                accum[3] / (118.0 * 158.0) + accum[4] / (58.0 * 78.0);
  mage /= (double)(NB * 4);
  out[0] = (float)(l1 + 0.5 * mage);
}

// ---------- launch ----------

extern "C" void kernel_launch(void* const* d_in, const int* in_sizes, int n_in,
                              void* d_out, int out_size, void* d_ws, size_t ws_size,
                              hipStream_t stream) {
  const float* pred = (const float*)d_in[0];
  const float* tgt = (const float*)d_in[1];
  float* out = (float*)d_out;
  char* ws = (char*)d_ws;

  double* accum = (double*)(ws + 0);            // 8 doubles (5 used)
  double* scsum = (double*)(ws + 64);           // 64 doubles
  unsigned* prefix = (unsigned*)(ws + 576);     // 64 u32
  int* kk = (int*)(ws + 832);                   // 64 i32
  float* shiftv = (float*)(ws + 1088);          // 64 f32
  unsigned* counts = (unsigned*)(ws + 1536);    // 64*256 u32 = 64 KB
  float* lvl1 = (float*)(ws + 67584);           // 64*240*320 f32 = 19.66 MB
  float* lvl2 = (float*)(ws + 19728384);        // 64*120*160 f32 = 4.92 MB
  float* lvl3 = (float*)(ws + 24643584);        // 64*60*80  f32 = 1.23 MB
  // total ws use ≈ 25.9 MB

  k_init<<<64, 256, 0, stream>>>(counts, prefix, kk, scsum, accum);
  for (int pass = 0; pass < 4; ++pass) {
    k_radix_count<<<dim3(16, NIMG), 256, 0, stream>>>(pred, tgt, counts, prefix, pass);
    k_radix_scan<<<NIMG, 256, 0, stream>>>(counts, prefix, kk);
  }
  k_median<<<1, 64, 0, stream>>>(prefix, shiftv);
  k_scale<<<dim3(16, NIMG), 256, 0, stream>>>(pred, tgt, shiftv, scsum);
  k_l1<<<dim3(32, NB), 256, 0, stream>>>(pred, tgt, shiftv, scsum, accum);
  k_grad0<<<dim3(64, NB), 256, 0, stream>>>(pred, tgt, scsum, accum + 1);
  k_down0<<<dim3(20, 15, NIMG), dim3(16, 16), 0, stream>>>(pred, tgt, shiftv, scsum, lvl1);
  k_grad<<<dim3(16, NB), 256, 0, stream>>>(lvl1, 240, 320, accum + 2);
  k_down<<<dim3(10, 8, NIMG), dim3(16, 16), 0, stream>>>(lvl1, lvl2, 240, 320);
  k_grad<<<dim3(8, NB), 256, 0, stream>>>(lvl2, 120, 160, accum + 3);
  k_down<<<dim3(5, 4, NIMG), dim3(16, 16), 0, stream>>>(lvl2, lvl3, 120, 160);
  k_grad<<<dim3(2, NB), 256, 0, stream>>>(lvl3, 60, 80, accum + 4);
  k_final<<<1, 1, 0, stream>>>(accum, out);
}

// Round 2
// 371.270 us; speedup vs baseline: 1.2992x; 1.2992x over previous
//
#include <hip/hip_runtime.h>
#include <stdint.h>
#include <math.h>

#define H0 480
#define W0 640
#define N0 (H0 * W0)
#define NB 32
#define NIMG 64
#define KRANK ((N0 - 1) / 2)
#define CAP 4096
#define NSLOT 128

// ---------- helpers ----------

static __device__ __forceinline__ unsigned fkey(float x) {
  unsigned b = __float_as_uint(x);
  return (b & 0x80000000u) ? ~b : (b | 0x80000000u);
}
static __device__ __forceinline__ float unkey(unsigned u) {
  unsigned b = (u & 0x80000000u) ? (u ^ 0x80000000u) : ~u;
  return __uint_as_float(b);
}

// two-value block reduction; result valid in thread 0. blockDim.x == 256.
static __device__ __forceinline__ void blockReduce2(float& a, float& b, int tid) {
#pragma unroll
  for (int o = 32; o > 0; o >>= 1) { a += __shfl_down(a, o); b += __shfl_down(b, o); }
  __shared__ float sa[4], sb[4];
  int lane = tid & 63, wid = tid >> 6;
  if (lane == 0) { sa[wid] = a; sb[wid] = b; }
  __syncthreads();
  if (wid == 0) {
    a = (lane < 4) ? sa[lane] : 0.f;
    b = (lane < 4) ? sb[lane] : 0.f;
    a += __shfl_down(a, 2); b += __shfl_down(b, 2);
    a += __shfl_down(a, 1); b += __shfl_down(b, 1);
  }
}

static __device__ __forceinline__ double blockReduceD(double v, int tid) {
#pragma unroll
  for (int o = 32; o > 0; o >>= 1) v += __shfl_down(v, o);
  __shared__ double sd[4];
  int lane = tid & 63, wid = tid >> 6;
  __syncthreads();
  if (lane == 0) sd[wid] = v;
  __syncthreads();
  if (wid == 0) {
    v = (lane < 4) ? sd[lane] : 0.0;
    v += __shfl_down(v, 2);
    v += __shfl_down(v, 1);
  }
  return v;
}

// ---------- init ----------

__global__ void k_init(unsigned* __restrict__ bcnt, float* __restrict__ bsum,
                       unsigned* __restrict__ prefix, int* __restrict__ kkrem,
                       unsigned* __restrict__ ccnt, double* __restrict__ accum) {
  int t = blockIdx.x * blockDim.x + threadIdx.x;  // 64*256 = 16384 exactly
  bcnt[t] = 0u;
  bsum[t] = 0.f;
  if (t < 5 * NSLOT) accum[t] = 0.0;
  if (t < NIMG) { prefix[t] = 0u; kkrem[t] = KRANK; ccnt[t] = 0u; }
}

// ---------- pass 1: top-byte histogram (counts + value sums) ----------

__global__ void k_hist0(const float* __restrict__ pred, const float* __restrict__ tgt,
                        unsigned* __restrict__ bcnt, float* __restrict__ bsum) {
  __shared__ unsigned hc[256][8];
  __shared__ float hs[256][8];
  int tid = threadIdx.x, img = blockIdx.y;
#pragma unroll
  for (int c = 0; c < 8; ++c) { hc[tid][c] = 0u; hs[tid][c] = 0.f; }
  __syncthreads();
  const float* src = (img < NB) ? pred + (size_t)img * N0 : tgt + (size_t)(img - NB) * N0;
  const float4* s4 = (const float4*)src;
  int c = tid & 7;
  int start = blockIdx.x * 256 + tid, stride = gridDim.x * 256;
  for (int i = start; i < N0 / 4; i += stride) {
    float4 v = s4[i];
    float vv[4] = {v.x, v.y, v.z, v.w};
#pragma unroll
    for (int j = 0; j < 4; ++j) {
      unsigned u = fkey(vv[j]) >> 24;
      atomicAdd(&hc[u][c], 1u);
      atomicAdd(&hs[u][c], vv[j]);
    }
  }
  __syncthreads();
  unsigned ct = 0;
  float st = 0.f;
#pragma unroll
  for (int k = 0; k < 8; ++k) { ct += hc[tid][k]; st += hs[tid][k]; }
  if (ct) {
    atomicAdd(&bcnt[img * 256 + tid], ct);
    atomicAdd(&bsum[img * 256 + tid], st);
  }
}

__global__ void k_scan0(const unsigned* __restrict__ bcnt, const float* __restrict__ bsum,
                        unsigned* __restrict__ prefix, int* __restrict__ kkrem,
                        double* __restrict__ cm1, double* __restrict__ sm1,
                        double* __restrict__ stot) {
  __shared__ unsigned c[256];
  __shared__ float s[256];
  int tid = threadIdx.x, img = blockIdx.x;
  c[tid] = bcnt[img * 256 + tid];
  s[tid] = bsum[img * 256 + tid];
  __syncthreads();
  if (tid == 0) {
    double tot = 0.0;
    for (int b = 0; b < 256; ++b) tot += (double)s[b];
    unsigned k = (unsigned)kkrem[img], cum = 0;
    double sc = 0.0;
    int b = 0;
    for (; b < 256; ++b) {
      unsigned cb = c[b];
      if (k < cum + cb) break;
      cum += cb;
      sc += (double)s[b];
    }
    prefix[img] = (unsigned)b;
    kkrem[img] = (int)(k - cum);
    cm1[img] = (double)cum;
    sm1[img] = sc;
    stot[img] = tot;
  }
}

// ---------- pass 2: collect candidates sharing the median's top byte ----------

__global__ void k_collect(const float* __restrict__ pred, const float* __restrict__ tgt,
                          const unsigned* __restrict__ prefix, unsigned* __restrict__ ccnt,
                          float* __restrict__ cand) {
  int tid = threadIdx.x, img = blockIdx.y;
  const float* src = (img < NB) ? pred + (size_t)img * N0 : tgt + (size_t)(img - NB) * N0;
  const float4* s4 = (const float4*)src;
  unsigned pref = prefix[img];
  int start = blockIdx.x * 256 + tid, stride = gridDim.x * 256;
  for (int i = start; i < N0 / 4; i += stride) {
    float4 v = s4[i];
    float vv[4] = {v.x, v.y, v.z, v.w};
#pragma unroll
    for (int j = 0; j < 4; ++j) {
      if ((fkey(vv[j]) >> 24) == pref) {
        unsigned pos = atomicAdd(&ccnt[img], 1u);
        if (pos < CAP) cand[(size_t)img * CAP + pos] = vv[j];
      }
    }
  }
}

// ---------- select: refine 24 bits, compute exact median + scale ----------

__global__ void k_select(const float* __restrict__ cand, const unsigned* __restrict__ ccnt,
                         const unsigned* __restrict__ prefix, const int* __restrict__ kkrem,
                         const double* __restrict__ cm1, const double* __restrict__ sm1,
                         const double* __restrict__ stot, float* __restrict__ shiftv,
                         float* __restrict__ invv) {
  __shared__ float cv[CAP];
  __shared__ unsigned hist[256];
  __shared__ unsigned shp;
  __shared__ int shk;
  int tid = threadIdx.x, img = blockIdx.x;
  int n = (int)min(ccnt[img], (unsigned)CAP);
  for (int i = tid; i < n; i += 256) cv[i] = cand[(size_t)img * CAP + i];
  unsigned pref = prefix[img];
  int krem = kkrem[img];
  __syncthreads();
  for (int p = 2; p >= 0; --p) {
    hist[tid] = 0u;
    __syncthreads();
    for (int i = tid; i < n; i += 256) {
      unsigned u = fkey(cv[i]);
      if ((u >> ((p + 1) * 8)) == pref) atomicAdd(&hist[(u >> (p * 8)) & 255u], 1u);
    }
    __syncthreads();
    if (tid == 0) {
      unsigned cum = 0;
      int b = 0;
      for (; b < 256; ++b) {
        unsigned cb = hist[b];
        if ((unsigned)krem < cum + cb) break;
        cum += cb;
      }
      shp = (pref << 8) | (unsigned)b;
      shk = krem - (int)cum;
    }
    __syncthreads();
    pref = shp;
    krem = shk;
  }
  unsigned mkey = pref;
  float m = unkey(mkey);
  float cc = 0.f, ss = 0.f;
  for (int i = tid; i < n; i += 256) {
    unsigned u = fkey(cv[i]);
    if (u < mkey) { cc += 1.f; ss += cv[i]; }
  }
  blockReduce2(cc, ss, tid);
  if (tid == 0) {
    double cminus = cm1[img] + (double)cc;
    double sminus = sm1[img] + (double)ss;
    double sumabs = stot[img] - 2.0 * sminus + (double)m * (2.0 * cminus - (double)N0);
    double scale = sumabs / (double)N0;
    shiftv[img] = m;
    invv[img] = (float)(1.0 / scale);
  }
}

// ---------- fused level 0: L1 + grad0 + down0 ----------
// ownership 32x64 input pixels per block; tile 36x68 (+halo), stride 69

__global__ __launch_bounds__(256) void k_f0(
    const float* __restrict__ pred, const float* __restrict__ tgt,
    const float* __restrict__ shiftv, const float* __restrict__ invv,
    float* __restrict__ lvl1, double* __restrict__ accum) {
  __shared__ float tp[36][69], tt[36][69];
  __shared__ float hp[36][32], ht[36][32];
  int tid = threadIdx.x;
  int b = blockIdx.z;
  int r0 = blockIdx.y * 32, c0 = blockIdx.x * 64;
  const float* P = pred + (size_t)b * N0;
  const float* T = tgt + (size_t)b * N0;
  float shpv = shiftv[b], ivp = invv[b], shtv = shiftv[NB + b], ivt = invv[NB + b];
  for (int idx = tid; idx < 36 * 68; idx += 256) {
    int r = idx / 68, cc_ = idx - r * 68;
    int gy = r0 - 2 + r, gx = c0 - 2 + cc_;
    bool in = (gy >= 0 && gy < H0 && gx >= 0 && gx < W0);
    size_t o = (size_t)gy * W0 + gx;
    tp[r][cc_] = in ? (P[o] - shpv) * ivp : 0.f;
    tt[r][cc_] = in ? (T[o] - shtv) * ivt : 0.f;
  }
  __syncthreads();
  float l1 = 0.f, g = 0.f;
  for (int idx = tid; idx < 32 * 64; idx += 256) {
    int rr = idx >> 6, cc2 = idx & 63;
    int tr = rr + 2, tc = cc2 + 2;
    l1 += fabsf(tp[tr][tc] - tt[tr][tc]);
    int gy = r0 + rr, gx = c0 + cc2;
    if (gy >= 1 && gy <= H0 - 2 && gx >= 1 && gx <= W0 - 2) {
      float a00 = tp[tr - 1][tc - 1], a01 = tp[tr - 1][tc], a02 = tp[tr - 1][tc + 1];
      float a10 = tp[tr][tc - 1], a12 = tp[tr][tc + 1];
      float a20 = tp[tr + 1][tc - 1], a21 = tp[tr + 1][tc], a22 = tp[tr + 1][tc + 1];
      float gx1 = 3.f * (a00 - a02) + 10.f * (a10 - a12) + 3.f * (a20 - a22);
      float gy1 = 3.f * (a00 - a20) + 10.f * (a01 - a21) + 3.f * (a02 - a22);
      float b00 = tt[tr - 1][tc - 1], b01 = tt[tr - 1][tc], b02 = tt[tr - 1][tc + 1];
      float b10 = tt[tr][tc - 1], b12 = tt[tr][tc + 1];
      float b20 = tt[tr + 1][tc - 1], b21 = tt[tr + 1][tc], b22 = tt[tr + 1][tc + 1];
      float hx = 3.f * (b00 - b02) + 10.f * (b10 - b12) + 3.f * (b20 - b22);
      float hy = 3.f * (b00 - b20) + 10.f * (b01 - b21) + 3.f * (b02 - b22);
      g += fabsf(sqrtf(gx1 * gx1 + gy1 * gy1) - sqrtf(hx * hx + hy * hy));
    }
  }
  const float K0 = 1.f / 32, K1 = 5.f / 32, K2 = 10.f / 32;
  for (int idx = tid; idx < 36 * 32; idx += 256) {
    int r = idx >> 5, j = idx & 31, c2 = 2 * j;
    hp[r][j] = (tp[r][c2] + tp[r][c2 + 5]) * K0 + (tp[r][c2 + 1] + tp[r][c2 + 4]) * K1 +
               (tp[r][c2 + 2] + tp[r][c2 + 3]) * K2;
    ht[r][j] = (tt[r][c2] + tt[r][c2 + 5]) * K0 + (tt[r][c2 + 1] + tt[r][c2 + 4]) * K1 +
               (tt[r][c2 + 2] + tt[r][c2 + 3]) * K2;
  }
  __syncthreads();
  for (int idx = tid; idx < 16 * 32 * 2; idx += 256) {
    int im2 = idx >> 9, i = (idx >> 5) & 15, j = idx & 31;
    float(*hs)[32] = im2 ? ht : hp;
    float v = (hs[2 * i][j] + hs[2 * i + 5][j]) * K0 +
              (hs[2 * i + 1][j] + hs[2 * i + 4][j]) * K1 +
              (hs[2 * i + 2][j] + hs[2 * i + 3][j]) * K2;
    int I = r0 / 2 + i, J = c0 / 2 + j;
    int img = b + im2 * NB;
    lvl1[(size_t)img * (240 * 320) + (size_t)I * 320 + J] = v;
  }
  blockReduce2(l1, g, tid);
  if (tid == 0) {
    int slot = (blockIdx.x + blockIdx.y * 10 + blockIdx.z * 150) & (NSLOT - 1);
    atomicAdd(&accum[0 * NSLOT + slot], (double)l1);
    atomicAdd(&accum[1 * NSLOT + slot], (double)g);
  }
}

// ---------- fused level k: grad + down ----------
// ownership 16x64; tile 20x68 stride 69

__global__ __launch_bounds__(256) void k_fk(const float* __restrict__ in,
                                            float* __restrict__ outd, int H, int W,
                                            double* __restrict__ accum) {
  __shared__ float tp[20][69], tt[20][69];
  __shared__ float hp[20][32], ht[20][32];
  int tid = threadIdx.x;
  int b = blockIdx.z;
  int r0 = blockIdx.y * 16, c0 = blockIdx.x * 64;
  const float* P = in + (size_t)b * H * W;
  const float* T = in + (size_t)(b + NB) * H * W;
  int Hout = H / 2, Wout = W / 2;
  for (int idx = tid; idx < 20 * 68; idx += 256) {
    int r = idx / 68, cc_ = idx - r * 68;
    int gy = r0 - 2 + r, gx = c0 - 2 + cc_;
    bool in_ = (gy >= 0 && gy < H && gx >= 0 && gx < W);
    size_t o = (size_t)gy * W + gx;
    tp[r][cc_] = in_ ? P[o] : 0.f;
    tt[r][cc_] = in_ ? T[o] : 0.f;
  }
  __syncthreads();
  float g = 0.f;
  for (int idx = tid; idx < 16 * 64; idx += 256) {
    int rr = idx >> 6, cc2 = idx & 63;
    int gy = r0 + rr, gx = c0 + cc2;
    if (gy >= 1 && gy <= H - 2 && gx >= 1 && gx <= W - 2) {
      int tr = rr + 2, tc = cc2 + 2;
      float a00 = tp[tr - 1][tc - 1], a01 = tp[tr - 1][tc], a02 = tp[tr - 1][tc + 1];
      float a10 = tp[tr][tc - 1], a12 = tp[tr][tc + 1];
      float a20 = tp[tr + 1][tc - 1], a21 = tp[tr + 1][tc], a22 = tp[tr + 1][tc + 1];
      float gx1 = 3.f * (a00 - a02) + 10.f * (a10 - a12) + 3.f * (a20 - a22);
      float gy1 = 3.f * (a00 - a20) + 10.f * (a01 - a21) + 3.f * (a02 - a22);
      float b00 = tt[tr - 1][tc - 1], b01 = tt[tr - 1][tc], b02 = tt[tr - 1][tc + 1];
      float b10 = tt[tr][tc - 1], b12 = tt[tr][tc + 1];
      float b20 = tt[tr + 1][tc - 1], b21 = tt[tr + 1][tc], b22 = tt[tr + 1][tc + 1];
      float hx = 3.f * (b00 - b02) + 10.f * (b10 - b12) + 3.f * (b20 - b22);
      float hy = 3.f * (b00 - b20) + 10.f * (b01 - b21) + 3.f * (b02 - b22);
      g += fabsf(sqrtf(gx1 * gx1 + gy1 * gy1) - sqrtf(hx * hx + hy * hy));
    }
  }
  const float K0 = 1.f / 32, K1 = 5.f / 32, K2 = 10.f / 32;
  for (int idx = tid; idx < 20 * 32; idx += 256) {
    int r = idx >> 5, j = idx & 31, c2 = 2 * j;
    hp[r][j] = (tp[r][c2] + tp[r][c2 + 5]) * K0 + (tp[r][c2 + 1] + tp[r][c2 + 4]) * K1 +
               (tp[r][c2 + 2] + tp[r][c2 + 3]) * K2;
    ht[r][j] = (tt[r][c2] + tt[r][c2 + 5]) * K0 + (tt[r][c2 + 1] + tt[r][c2 + 4]) * K1 +
               (tt[r][c2 + 2] + tt[r][c2 + 3]) * K2;
  }
  __syncthreads();
  for (int idx = tid; idx < 8 * 32 * 2; idx += 256) {
    int im2 = idx >> 8, i = (idx >> 5) & 7, j = idx & 31;
    float(*hs)[32] = im2 ? ht : hp;
    float v = (hs[2 * i][j] + hs[2 * i + 5][j]) * K0 +
              (hs[2 * i + 1][j] + hs[2 * i + 4][j]) * K1 +
              (hs[2 * i + 2][j] + hs[2 * i + 3][j]) * K2;
    int I = r0 / 2 + i, J = c0 / 2 + j;
    if (I < Hout && J < Wout) {
      int img = b + im2 * NB;
      outd[(size_t)img * Hout * Wout + (size_t)I * Wout + J] = v;
    }
  }
  float dummy = 0.f;
  blockReduce2(g, dummy, tid);
  if (tid == 0) {
    int slot = (blockIdx.x + blockIdx.y * gridDim.x + blockIdx.z * gridDim.x * gridDim.y) &
               (NSLOT - 1);
    atomicAdd(&accum[slot], (double)g);
  }
}

// ---------- level 3 grad only (60x80, L2-resident) ----------

__global__ void k_g3(const float* __restrict__ buf, double* __restrict__ accum) {
  int b = blockIdx.y;
  const float* p = buf + (size_t)b * (60 * 80);
  const float* t = buf + (size_t)(b + NB) * (60 * 80);
  const int VW = 78, NV = 58 * 78;
  float acc = 0.f;
  int start = blockIdx.x * blockDim.x + threadIdx.x, stride = gridDim.x * blockDim.x;
  for (int idx = start; idx < NV; idx += stride) {
    int y = idx / VW, x = idx - y * VW;
    const float* pr = p + (size_t)y * 80 + x;
    float a00 = pr[0], a01 = pr[1], a02 = pr[2];
    float a10 = pr[80], a12 = pr[82];
    float a20 = pr[160], a21 = pr[161], a22 = pr[162];
    float gx1 = 3.f * (a00 - a02) + 10.f * (a10 - a12) + 3.f * (a20 - a22);
    float gy1 = 3.f * (a00 - a20) + 10.f * (a01 - a21) + 3.f * (a02 - a22);
    const float* tr = t + (size_t)y * 80 + x;
    float b00 = tr[0], b01 = tr[1], b02 = tr[2];
    float b10 = tr[80], b12 = tr[82];
    float b20 = tr[160], b21 = tr[161], b22 = tr[162];
    float hx = 3.f * (b00 - b02) + 10.f * (b10 - b12) + 3.f * (b20 - b22);
    float hy = 3.f * (b00 - b20) + 10.f * (b01 - b21) + 3.f * (b02 - b22);
    acc += fabsf(sqrtf(gx1 * gx1 + gy1 * gy1) - sqrtf(hx * hx + hy * hy));
  }
  float d = 0.f;
  blockReduce2(acc, d, threadIdx.x);
  if (threadIdx.x == 0) {
    int slot = (blockIdx.x + blockIdx.y * gridDim.x) & (NSLOT - 1);
    atomicAdd(&accum[slot], (double)acc);
  }
}

// ---------- finalize ----------

__global__ void k_final(const double* __restrict__ accum, float* __restrict__ out) {
  int tid = threadIdx.x;  // 256
  double m[5];
#pragma unroll
  for (int k = 0; k < 5; ++k) {
    double v = (tid < NSLOT) ? accum[k * NSLOT + tid] : 0.0;
    m[k] = blockReduceD(v, tid);
  }
  if (tid == 0) {
    double l1 = m[0] / ((double)NB * (double)N0 * 2.0);
    double mage = m[1] / (478.0 * 638.0) + m[2] / (238.0 * 318.0) + m[3] / (118.0 * 158.0) +
                  m[4] / (58.0 * 78.0);
    mage /= (double)(NB * 4);
    out[0] = (float)(l1 + 0.5 * mage);
  }
}

// ---------- launch ----------

extern "C" void kernel_launch(void* const* d_in, const int* in_sizes, int n_in,
                              void* d_out, int out_size, void* d_ws, size_t ws_size,
                              hipStream_t stream) {
  const float* pred = (const float*)d_in[0];
  const float* tgt = (const float*)d_in[1];
  float* out = (float*)d_out;
  char* ws = (char*)d_ws;

  // persistent region
  double* accum = (double*)(ws + 0);        // 5*128 doubles = 5120 B
  float* shiftv = (float*)(ws + 5120);      // 64 f32
  float* invv = (float*)(ws + 5376);        // 64 f32
  // median-phase scratch (overlaps pyramid; strictly earlier in the stream)
  unsigned* bcnt = (unsigned*)(ws + 8192);    // 64*256 u32 = 64 KB
  float* bsum = (float*)(ws + 73728);         // 64*256 f32 = 64 KB
  unsigned* prefix = (unsigned*)(ws + 139264);
  int* kkrem = (int*)(ws + 139520);
  double* cm1 = (double*)(ws + 139776);
  double* sm1 = (double*)(ws + 140288);
  double* stot = (double*)(ws + 140800);
  unsigned* ccnt = (unsigned*)(ws + 141312);
  float* cand = (float*)(ws + 141568);        // 64*4096 f32 = 1 MB
  // pyramid (used after median phase completes)
  float* lvl1 = (float*)(ws + 8192);          // 64*240*320 f32 = 19.66 MB
  float* lvl2 = (float*)(ws + 19668992);      // 64*120*160 f32 = 4.92 MB
  float* lvl3 = (float*)(ws + 24584192);      // 64*60*80 f32 = 1.23 MB
  // total ws use = 25,812,992 B (< round-1's validated 25.9 MB)

  k_init<<<64, 256, 0, stream>>>(bcnt, bsum, prefix, kkrem, ccnt, accum);
  k_hist0<<<dim3(16, NIMG), 256, 0, stream>>>(pred, tgt, bcnt, bsum);
  k_scan0<<<NIMG, 256, 0, stream>>>(bcnt, bsum, prefix, kkrem, cm1, sm1, stot);
  k_collect<<<dim3(16, NIMG), 256, 0, stream>>>(pred, tgt, prefix, ccnt, cand);
  k_select<<<NIMG, 256, 0, stream>>>(cand, ccnt, prefix, kkrem, cm1, sm1, stot, shiftv, invv);
  k_f0<<<dim3(10, 15, NB), 256, 0, stream>>>(pred, tgt, shiftv, invv, lvl1, accum);
  k_fk<<<dim3(5, 15, NB), 256, 0, stream>>>(lvl1, lvl2, 240, 320, accum + 2 * NSLOT);
  k_fk<<<dim3(3, 8, NB), 256, 0, stream>>>(lvl2, lvl3, 120, 160, accum + 3 * NSLOT);
  k_g3<<<dim3(2, NB), 256, 0, stream>>>(lvl3, accum + 4 * NSLOT);
  k_final<<<1, 256, 0, stream>>>(accum, out);
}

// Round 3
// 137.437 us; speedup vs baseline: 3.5098x; 2.7014x over previous
//
#include <hip/hip_runtime.h>
#include <stdint.h>
#include <math.h>

#define H0 480
#define W0 640
#define N0 (H0 * W0)
#define NB 32
#define NIMG 64
#define NSLOT 128

// ---------- helpers ----------

static __device__ __forceinline__ unsigned fkey(float x) {
  unsigned b = __float_as_uint(x);
  return (b & 0x80000000u) ? ~b : (b | 0x80000000u);
}
static __device__ __forceinline__ float unkey(unsigned u) {
  unsigned b = (u & 0x80000000u) ? (u ^ 0x80000000u) : ~u;
  return __uint_as_float(b);
}

// two-value block reduction; result valid in thread 0. blockDim.x == 256.
static __device__ __forceinline__ void blockReduce2(float& a, float& b, int tid) {
#pragma unroll
  for (int o = 32; o > 0; o >>= 1) { a += __shfl_down(a, o); b += __shfl_down(b, o); }
  __shared__ float sa[4], sb[4];
  int lane = tid & 63, wid = tid >> 6;
  if (lane == 0) { sa[wid] = a; sb[wid] = b; }
  __syncthreads();
  if (wid == 0) {
    a = (lane < 4) ? sa[lane] : 0.f;
    b = (lane < 4) ? sb[lane] : 0.f;
    a += __shfl_down(a, 2); b += __shfl_down(b, 2);
    a += __shfl_down(a, 1); b += __shfl_down(b, 1);
  }
}

static __device__ __forceinline__ double blockReduceD(double v, int tid) {
#pragma unroll
  for (int o = 32; o > 0; o >>= 1) v += __shfl_down(v, o);
  __shared__ double sd[4];
  int lane = tid & 63, wid = tid >> 6;
  __syncthreads();
  if (lane == 0) sd[wid] = v;
  __syncthreads();
  if (wid == 0) {
    v = (lane < 4) ? sd[lane] : 0.0;
    v += __shfl_down(v, 2);
    v += __shfl_down(v, 1);
  }
  return v;
}

// ---------- init ----------

__global__ void k_init(unsigned* __restrict__ bcnt, double* __restrict__ scsum,
                       double* __restrict__ accum) {
  int t = blockIdx.x * blockDim.x + threadIdx.x;  // 64*256 = 16384 exactly
  bcnt[t] = 0u;
  if (t < 5 * NSLOT) accum[t] = 0.0;
  if (t < NIMG) scsum[t] = 0.0;
}

// ---------- pass 1: top-byte histogram, stride-2 subsample, counts only ----------

__global__ void k_hist(const float* __restrict__ pred, const float* __restrict__ tgt,
                       unsigned* __restrict__ bcnt) {
  __shared__ unsigned hc[256][8];  // 8-way replicated
  int tid = threadIdx.x, img = blockIdx.y;
#pragma unroll
  for (int c = 0; c < 8; ++c) hc[tid][c] = 0u;
  __syncthreads();
  const float* src = (img < NB) ? pred + (size_t)img * N0 : tgt + (size_t)(img - NB) * N0;
  const float4* s4 = (const float4*)src;
  int c = tid & 7;
  int start = blockIdx.x * 256 + tid, stride = gridDim.x * 256;
  for (int i = start; i < N0 / 4; i += stride) {
    float4 v = s4[i];
    atomicAdd(&hc[fkey(v.x) >> 24][c], 1u);
    atomicAdd(&hc[fkey(v.z) >> 24][c], 1u);
  }
  __syncthreads();
  unsigned ct = 0;
#pragma unroll
  for (int k = 0; k < 8; ++k) ct += hc[tid][k];
  if (ct) atomicAdd(&bcnt[img * 256 + tid], ct);
}

// ---------- interpolated median per image ----------

__global__ void k_med(const unsigned* __restrict__ bcnt, float* __restrict__ shiftv) {
  __shared__ unsigned c[256];
  int tid = threadIdx.x, img = blockIdx.x;
  c[tid] = bcnt[img * 256 + tid];
  __syncthreads();
  if (tid == 0) {
    unsigned total = 0;
    for (int b = 0; b < 256; ++b) total += c[b];
    float k = 0.5f * (float)(total - 1);
    unsigned cum = 0;
    int b = 0;
    for (; b < 256; ++b) {
      if (k < (float)(cum + c[b])) break;
      cum += c[b];
    }
    if (b > 255) b = 255;
    unsigned cb = c[b] ? c[b] : 1u;
    float frac = (k - (float)cum + 0.5f) / (float)cb;
    frac = fminf(fmaxf(frac, 0.f), 1.f);
    unsigned klo = (unsigned)b << 24;
    unsigned khi = (b == 255) ? 0xFFFFFFFFu : ((unsigned)(b + 1) << 24);
    float lo = unkey(klo), hi = unkey(khi);
    float m = lo + frac * (hi - lo);
    if (!isfinite(m)) m = isfinite(lo) ? lo : (isfinite(hi) ? hi : 0.f);
    shiftv[img] = m;
  }
}

// ---------- scale = sum |x - shift| (pure reduction) ----------

__global__ void k_scale(const float* __restrict__ pred, const float* __restrict__ tgt,
                        const float* __restrict__ shiftv, double* __restrict__ scsum) {
  int tid = threadIdx.x, img = blockIdx.y;
  const float* src = (img < NB) ? pred + (size_t)img * N0 : tgt + (size_t)(img - NB) * N0;
  const float4* s4 = (const float4*)src;
  float sh = shiftv[img];
  float acc = 0.f;
  int start = blockIdx.x * 256 + tid, stride = gridDim.x * 256;
  for (int i = start; i < N0 / 4; i += stride) {
    float4 v = s4[i];
    acc += fabsf(v.x - sh) + fabsf(v.y - sh) + fabsf(v.z - sh) + fabsf(v.w - sh);
  }
  float d = 0.f;
  blockReduce2(acc, d, tid);
  if (tid == 0) atomicAdd(&scsum[img], (double)acc);
}

// ---------- fused level 0: L1 + grad0 + down0 ----------
// ownership 32x64 input pixels per block; tile 36x68 (+halo), stride 69

__global__ __launch_bounds__(256) void k_f0(
    const float* __restrict__ pred, const float* __restrict__ tgt,
    const float* __restrict__ shiftv, const double* __restrict__ scsum,
    float* __restrict__ lvl1, double* __restrict__ accum) {
  __shared__ float tp[36][69], tt[36][69];
  __shared__ float hp[36][32], ht[36][32];
  int tid = threadIdx.x;
  int b = blockIdx.z;
  int r0 = blockIdx.y * 32, c0 = blockIdx.x * 64;
  const float* P = pred + (size_t)b * N0;
  const float* T = tgt + (size_t)b * N0;
  float shpv = shiftv[b], shtv = shiftv[NB + b];
  float ivp = (float)((double)N0 / scsum[b]);
  float ivt = (float)((double)N0 / scsum[NB + b]);
  for (int idx = tid; idx < 36 * 68; idx += 256) {
    int r = idx / 68, cc_ = idx - r * 68;
    int gy = r0 - 2 + r, gx = c0 - 2 + cc_;
    bool in = (gy >= 0 && gy < H0 && gx >= 0 && gx < W0);
    size_t o = (size_t)gy * W0 + gx;
    tp[r][cc_] = in ? (P[o] - shpv) * ivp : 0.f;
    tt[r][cc_] = in ? (T[o] - shtv) * ivt : 0.f;
  }
  __syncthreads();
  float l1 = 0.f, g = 0.f;
  for (int idx = tid; idx < 32 * 64; idx += 256) {
    int rr = idx >> 6, cc2 = idx & 63;
    int tr = rr + 2, tc = cc2 + 2;
    l1 += fabsf(tp[tr][tc] - tt[tr][tc]);
    int gy = r0 + rr, gx = c0 + cc2;
    if (gy >= 1 && gy <= H0 - 2 && gx >= 1 && gx <= W0 - 2) {
      float a00 = tp[tr - 1][tc - 1], a01 = tp[tr - 1][tc], a02 = tp[tr - 1][tc + 1];
      float a10 = tp[tr][tc - 1], a12 = tp[tr][tc + 1];
      float a20 = tp[tr + 1][tc - 1], a21 = tp[tr + 1][tc], a22 = tp[tr + 1][tc + 1];
      float gx1 = 3.f * (a00 - a02) + 10.f * (a10 - a12) + 3.f * (a20 - a22);
      float gy1 = 3.f * (a00 - a20) + 10.f * (a01 - a21) + 3.f * (a02 - a22);
      float b00 = tt[tr - 1][tc - 1], b01 = tt[tr - 1][tc], b02 = tt[tr - 1][tc + 1];
      float b10 = tt[tr][tc - 1], b12 = tt[tr][tc + 1];
      float b20 = tt[tr + 1][tc - 1], b21 = tt[tr + 1][tc], b22 = tt[tr + 1][tc + 1];
      float hx = 3.f * (b00 - b02) + 10.f * (b10 - b12) + 3.f * (b20 - b22);
      float hy = 3.f * (b00 - b20) + 10.f * (b01 - b21) + 3.f * (b02 - b22);
      g += fabsf(sqrtf(gx1 * gx1 + gy1 * gy1) - sqrtf(hx * hx + hy * hy));
    }
  }
  const float K0 = 1.f / 32, K1 = 5.f / 32, K2 = 10.f / 32;
  for (int idx = tid; idx < 36 * 32; idx += 256) {
    int r = idx >> 5, j = idx & 31, c2 = 2 * j;
    hp[r][j] = (tp[r][c2] + tp[r][c2 + 5]) * K0 + (tp[r][c2 + 1] + tp[r][c2 + 4]) * K1 +
               (tp[r][c2 + 2] + tp[r][c2 + 3]) * K2;
    ht[r][j] = (tt[r][c2] + tt[r][c2 + 5]) * K0 + (tt[r][c2 + 1] + tt[r][c2 + 4]) * K1 +
               (tt[r][c2 + 2] + tt[r][c2 + 3]) * K2;
  }
  __syncthreads();
  for (int idx = tid; idx < 16 * 32 * 2; idx += 256) {
    int im2 = idx >> 9, i = (idx >> 5) & 15, j = idx & 31;
    float(*hs)[32] = im2 ? ht : hp;
    float v = (hs[2 * i][j] + hs[2 * i + 5][j]) * K0 +
              (hs[2 * i + 1][j] + hs[2 * i + 4][j]) * K1 +
              (hs[2 * i + 2][j] + hs[2 * i + 3][j]) * K2;
    int I = r0 / 2 + i, J = c0 / 2 + j;
    int img = b + im2 * NB;
    lvl1[(size_t)img * (240 * 320) + (size_t)I * 320 + J] = v;
  }
  blockReduce2(l1, g, tid);
  if (tid == 0) {
    int slot = (blockIdx.x + blockIdx.y * 10 + blockIdx.z * 150) & (NSLOT - 1);
    atomicAdd(&accum[0 * NSLOT + slot], (double)l1);
    atomicAdd(&accum[1 * NSLOT + slot], (double)g);
  }
}

// ---------- fused level k: grad + down ----------
// ownership 16x64; tile 20x68 stride 69

__global__ __launch_bounds__(256) void k_fk(const float* __restrict__ in,
                                            float* __restrict__ outd, int H, int W,
                                            double* __restrict__ accum) {
  __shared__ float tp[20][69], tt[20][69];
  __shared__ float hp[20][32], ht[20][32];
  int tid = threadIdx.x;
  int b = blockIdx.z;
  int r0 = blockIdx.y * 16, c0 = blockIdx.x * 64;
  const float* P = in + (size_t)b * H * W;
  const float* T = in + (size_t)(b + NB) * H * W;
  int Hout = H / 2, Wout = W / 2;
  for (int idx = tid; idx < 20 * 68; idx += 256) {
    int r = idx / 68, cc_ = idx - r * 68;
    int gy = r0 - 2 + r, gx = c0 - 2 + cc_;
    bool in_ = (gy >= 0 && gy < H && gx >= 0 && gx < W);
    size_t o = (size_t)gy * W + gx;
    tp[r][cc_] = in_ ? P[o] : 0.f;
    tt[r][cc_] = in_ ? T[o] : 0.f;
  }
  __syncthreads();
  float g = 0.f;
  for (int idx = tid; idx < 16 * 64; idx += 256) {
    int rr = idx >> 6, cc2 = idx & 63;
    int gy = r0 + rr, gx = c0 + cc2;
    if (gy >= 1 && gy <= H - 2 && gx >= 1 && gx <= W - 2) {
      int tr = rr + 2, tc = cc2 + 2;
      float a00 = tp[tr - 1][tc - 1], a01 = tp[tr - 1][tc], a02 = tp[tr - 1][tc + 1];
      float a10 = tp[tr][tc - 1], a12 = tp[tr][tc + 1];
      float a20 = tp[tr + 1][tc - 1], a21 = tp[tr + 1][tc], a22 = tp[tr + 1][tc + 1];
      float gx1 = 3.f * (a00 - a02) + 10.f * (a10 - a12) + 3.f * (a20 - a22);
      float gy1 = 3.f * (a00 - a20) + 10.f * (a01 - a21) + 3.f * (a02 - a22);
      float b00 = tt[tr - 1][tc - 1], b01 = tt[tr - 1][tc], b02 = tt[tr - 1][tc + 1];
      float b10 = tt[tr][tc - 1], b12 = tt[tr][tc + 1];
      float b20 = tt[tr + 1][tc - 1], b21 = tt[tr + 1][tc], b22 = tt[tr + 1][tc + 1];
      float hx = 3.f * (b00 - b02) + 10.f * (b10 - b12) + 3.f * (b20 - b22);
      float hy = 3.f * (b00 - b20) + 10.f * (b01 - b21) + 3.f * (b02 - b22);
      g += fabsf(sqrtf(gx1 * gx1 + gy1 * gy1) - sqrtf(hx * hx + hy * hy));
    }
  }
  const float K0 = 1.f / 32, K1 = 5.f / 32, K2 = 10.f / 32;
  for (int idx = tid; idx < 20 * 32; idx += 256) {
    int r = idx >> 5, j = idx & 31, c2 = 2 * j;
    hp[r][j] = (tp[r][c2] + tp[r][c2 + 5]) * K0 + (tp[r][c2 + 1] + tp[r][c2 + 4]) * K1 +
               (tp[r][c2 + 2] + tp[r][c2 + 3]) * K2;
    ht[r][j] = (tt[r][c2] + tt[r][c2 + 5]) * K0 + (tt[r][c2 + 1] + tt[r][c2 + 4]) * K1 +
               (tt[r][c2 + 2] + tt[r][c2 + 3]) * K2;
  }
  __syncthreads();
  for (int idx = tid; idx < 8 * 32 * 2; idx += 256) {
    int im2 = idx >> 8, i = (idx >> 5) & 7, j = idx & 31;
    float(*hs)[32] = im2 ? ht : hp;
    float v = (hs[2 * i][j] + hs[2 * i + 5][j]) * K0 +
              (hs[2 * i + 1][j] + hs[2 * i + 4][j]) * K1 +
              (hs[2 * i + 2][j] + hs[2 * i + 3][j]) * K2;
    int I = r0 / 2 + i, J = c0 / 2 + j;
    if (I < Hout && J < Wout) {
      int img = b + im2 * NB;
      outd[(size_t)img * Hout * Wout + (size_t)I * Wout + J] = v;
    }
  }
  float dummy = 0.f;
  blockReduce2(g, dummy, tid);
  if (tid == 0) {
    int slot = (blockIdx.x + blockIdx.y * gridDim.x + blockIdx.z * gridDim.x * gridDim.y) &
               (NSLOT - 1);
    atomicAdd(&accum[slot], (double)g);
  }
}

// ---------- level 3 grad only (60x80, L2-resident) ----------

__global__ void k_g3(const float* __restrict__ buf, double* __restrict__ accum) {
  int b = blockIdx.y;
  const float* p = buf + (size_t)b * (60 * 80);
  const float* t = buf + (size_t)(b + NB) * (60 * 80);
  const int VW = 78, NV = 58 * 78;
  float acc = 0.f;
  int start = blockIdx.x * blockDim.x + threadIdx.x, stride = gridDim.x * blockDim.x;
  for (int idx = start; idx < NV; idx += stride) {
    int y = idx / VW, x = idx - y * VW;
    const float* pr = p + (size_t)y * 80 + x;
    float a00 = pr[0], a01 = pr[1], a02 = pr[2];
    float a10 = pr[80], a12 = pr[82];
    float a20 = pr[160], a21 = pr[161], a22 = pr[162];
    float gx1 = 3.f * (a00 - a02) + 10.f * (a10 - a12) + 3.f * (a20 - a22);
    float gy1 = 3.f * (a00 - a20) + 10.f * (a01 - a21) + 3.f * (a02 - a22);
    const float* tr = t + (size_t)y * 80 + x;
    float b00 = tr[0], b01 = tr[1], b02 = tr[2];
    float b10 = tr[80], b12 = tr[82];
    float b20 = tr[160], b21 = tr[161], b22 = tr[162];
    float hx = 3.f * (b00 - b02) + 10.f * (b10 - b12) + 3.f * (b20 - b22);
    float hy = 3.f * (b00 - b20) + 10.f * (b01 - b21) + 3.f * (b02 - b22);
    acc += fabsf(sqrtf(gx1 * gx1 + gy1 * gy1) - sqrtf(hx * hx + hy * hy));
  }
  float d = 0.f;
  blockReduce2(acc, d, threadIdx.x);
  if (threadIdx.x == 0) {
    int slot = (blockIdx.x + blockIdx.y * gridDim.x) & (NSLOT - 1);
    atomicAdd(&accum[slot], (double)acc);
  }
}

// ---------- finalize ----------

__global__ void k_final(const double* __restrict__ accum, float* __restrict__ out) {
  int tid = threadIdx.x;  // 256
  double m[5];
#pragma unroll
  for (int k = 0; k < 5; ++k) {
    double v = (tid < NSLOT) ? accum[k * NSLOT + tid] : 0.0;
    m[k] = blockReduceD(v, tid);
  }
  if (tid == 0) {
    double l1 = m[0] / ((double)NB * (double)N0 * 2.0);
    double mage = m[1] / (478.0 * 638.0) + m[2] / (238.0 * 318.0) + m[3] / (118.0 * 158.0) +
                  m[4] / (58.0 * 78.0);
    mage /= (double)(NB * 4);
    out[0] = (float)(l1 + 0.5 * mage);
  }
}

// ---------- launch ----------

extern "C" void kernel_launch(void* const* d_in, const int* in_sizes, int n_in,
                              void* d_out, int out_size, void* d_ws, size_t ws_size,
                              hipStream_t stream) {
  const float* pred = (const float*)d_in[0];
  const float* tgt = (const float*)d_in[1];
  float* out = (float*)d_out;
  char* ws = (char*)d_ws;

  double* accum = (double*)(ws + 0);      // 5*128 doubles = 5120 B
  float* shiftv = (float*)(ws + 5120);    // 64 f32
  double* scsum = (double*)(ws + 5376);   // 64 doubles -> ends 5888
  // bcnt overlaps lvl1: hist/med finish (stream-ordered) before f0 writes lvl1
  unsigned* bcnt = (unsigned*)(ws + 8192);  // 64*256 u32 = 64 KB
  float* lvl1 = (float*)(ws + 8192);        // 64*240*320 f32 = 19.66 MB
  float* lvl2 = (float*)(ws + 19668992);    // 64*120*160 f32 = 4.92 MB
  float* lvl3 = (float*)(ws + 24584192);    // 64*60*80 f32 = 1.23 MB -> 25,812,992 total

  k_init<<<64, 256, 0, stream>>>(bcnt, scsum, accum);
  k_hist<<<dim3(16, NIMG), 256, 0, stream>>>(pred, tgt, bcnt);
  k_med<<<NIMG, 256, 0, stream>>>(bcnt, shiftv);
  k_scale<<<dim3(16, NIMG), 256, 0, stream>>>(pred, tgt, shiftv, scsum);
  k_f0<<<dim3(10, 15, NB), 256, 0, stream>>>(pred, tgt, shiftv, scsum, lvl1, accum);
  k_fk<<<dim3(5, 15, NB), 256, 0, stream>>>(lvl1, lvl2, 240, 320, accum + 2 * NSLOT);
  k_fk<<<dim3(3, 8, NB), 256, 0, stream>>>(lvl2, lvl3, 120, 160, accum + 3 * NSLOT);
  k_g3<<<dim3(2, NB), 256, 0, stream>>>(lvl3, accum + 4 * NSLOT);
  k_final<<<1, 256, 0, stream>>>(accum, out);
}